// Round 1
// baseline (1620.948 us; speedup 1.0000x reference)
//
#include <hip/hip_runtime.h>

// Simple GNN: h = X@W_in+b; 4x { agg = segsum(w*h[src], dst)/deg; h += lrelu(agg@W_l+b_l) }
// out = (h@W_out+b_out, h)

#define N_NODES 50000
#define N_EDGES 625000
#define IN_F 64
#define INT_F 128
#define OUT_F 32
#define DEPTH 4
#define NEG_SLOPE 0.01f

// ---- count in-degree (float) ----
__global__ void count_kernel(const int2* __restrict__ ei, float* __restrict__ counts) {
    int i = blockIdx.x * blockDim.x + threadIdx.x;
    if (i < N_EDGES) atomicAdd(&counts[ei[i].y], 1.0f);
}

// ---- h = X @ W_in + b_in  (one node per 128-thread block) ----
__global__ void gemm_in_kernel(const float* __restrict__ X, const float* __restrict__ W,
                               const float* __restrict__ b, float* __restrict__ h) {
    int node = blockIdx.x;
    int f = threadIdx.x;  // 0..127
    __shared__ float xr[IN_F];
    if (f < IN_F) xr[f] = X[node * IN_F + f];
    __syncthreads();
    float acc = b[f];
#pragma unroll
    for (int k = 0; k < IN_F; ++k) acc += xr[k] * W[k * INT_F + f];
    h[node * INT_F + f] = acc;
}

// ---- scatter: agg[dst] += w * h[src], one thread per (edge, feature) ----
__global__ void scatter_kernel(const int2* __restrict__ ei, const float* __restrict__ ew,
                               const float* __restrict__ h, float* __restrict__ agg) {
    int idx = blockIdx.x * blockDim.x + threadIdx.x;  // < 80,000,000, fits int32
    if (idx >= N_EDGES * INT_F) return;
    int e = idx >> 7;        // / 128
    int f = idx & (INT_F - 1);
    int2 sd = ei[e];
    float val = ew[e] * h[(size_t)sd.x * INT_F + f];
    atomicAdd(&agg[(size_t)sd.y * INT_F + f], val);
}

// ---- z = (agg/deg) @ W + b ; h += lrelu(z)  (one node per 128-thread block) ----
__global__ void layer_kernel(const float* __restrict__ agg, const float* __restrict__ counts,
                             const float* __restrict__ W, const float* __restrict__ b,
                             float* __restrict__ h) {
    int node = blockIdx.x;
    int f = threadIdx.x;  // 0..127
    __shared__ float ar[INT_F];
    float inv = 1.0f / fmaxf(counts[node], 1.0f);
    ar[f] = agg[node * INT_F + f] * inv;
    __syncthreads();
    float acc = b[f];
#pragma unroll 8
    for (int k = 0; k < INT_F; ++k) acc += ar[k] * W[k * INT_F + f];
    float z = acc;
    h[node * INT_F + f] += (z >= 0.0f) ? z : NEG_SLOPE * z;
}

// ---- out = h @ W_out + b_out  (8 nodes per 256-thread block) ----
__global__ void gemm_out_kernel(const float* __restrict__ h, const float* __restrict__ W,
                                const float* __restrict__ b, float* __restrict__ out) {
    __shared__ float hr[8][INT_F];
    int base = blockIdx.x * 8;
    for (int t = threadIdx.x; t < 8 * INT_F; t += 256) {
        int n = t / INT_F, k = t % INT_F;
        int gn = base + n;
        hr[n][k] = (gn < N_NODES) ? h[(size_t)gn * INT_F + k] : 0.0f;
    }
    __syncthreads();
    int nl = threadIdx.x / OUT_F;  // 0..7
    int f = threadIdx.x % OUT_F;
    int node = base + nl;
    if (node >= N_NODES) return;
    float acc = b[f];
#pragma unroll 8
    for (int k = 0; k < INT_F; ++k) acc += hr[nl][k] * W[k * OUT_F + f];
    out[(size_t)node * OUT_F + f] = acc;
}

extern "C" void kernel_launch(void* const* d_in, const int* in_sizes, int n_in,
                              void* d_out, int out_size, void* d_ws, size_t ws_size,
                              hipStream_t stream) {
    const float* X        = (const float*)d_in[0];
    const int2*  ei       = (const int2*)d_in[1];
    const float* ew       = (const float*)d_in[2];
    const float* W_in     = (const float*)d_in[3];
    const float* b_in     = (const float*)d_in[4];
    const float* W_layers = (const float*)d_in[5];
    const float* b_layers = (const float*)d_in[6];
    const float* W_out    = (const float*)d_in[7];
    const float* b_out    = (const float*)d_in[8];

    float* out1 = (float*)d_out;                      // (N_NODES, OUT_F)
    float* h    = out1 + (size_t)N_NODES * OUT_F;     // (N_NODES, INT_F) -- second output, used as h buffer

    float* agg    = (float*)d_ws;                     // (N_NODES, INT_F)
    float* counts = agg + (size_t)N_NODES * INT_F;    // (N_NODES,)

    // in-degree (once, reused for all layers)
    hipMemsetAsync(counts, 0, N_NODES * sizeof(float), stream);
    count_kernel<<<(N_EDGES + 255) / 256, 256, 0, stream>>>(ei, counts);

    // input projection
    gemm_in_kernel<<<N_NODES, INT_F, 0, stream>>>(X, W_in, b_in, h);

    // layers
    for (int i = 0; i < DEPTH; ++i) {
        hipMemsetAsync(agg, 0, (size_t)N_NODES * INT_F * sizeof(float), stream);
        int total = N_EDGES * INT_F;
        scatter_kernel<<<(total + 255) / 256, 256, 0, stream>>>(ei, ew, h, agg);
        layer_kernel<<<N_NODES, INT_F, 0, stream>>>(
            agg, counts, W_layers + (size_t)i * INT_F * INT_F, b_layers + (size_t)i * INT_F, h);
    }

    // output projection
    gemm_out_kernel<<<(N_NODES + 7) / 8, 256, 0, stream>>>(h, W_out, b_out, out1);
}

// Round 2
// 670.721 us; speedup vs baseline: 2.4167x; 2.4167x over previous
//
#include <hip/hip_runtime.h>

// Simple GNN: h = X@W_in+b; 4x { agg = segmean(w*h[src], dst); h += lrelu(agg@W_l+b_l) }
// out = (h@W_out+b_out, h)
// Round 2: CSR-by-dst gather aggregation (no float atomics), 16-node-batched GEMMs.

#define N_NODES 50000
#define N_EDGES 625000
#define IN_F 64
#define INT_F 128
#define OUT_F 32
#define DEPTH 4
#define NEG_SLOPE 0.01f

// ---- in-degree (int) ----
__global__ void deg_kernel(const int2* __restrict__ ei, int* __restrict__ deg) {
    int i = blockIdx.x * blockDim.x + threadIdx.x;
    if (i < N_EDGES) atomicAdd(&deg[ei[i].y], 1);
}

// ---- single-block exclusive scan: deg[50000] -> row_ptr[50001], cursor=row_ptr ----
__global__ void scan_kernel(const int* __restrict__ deg, int* __restrict__ row_ptr,
                            int* __restrict__ cursor) {
    __shared__ int ps[1024];
    const int t = threadIdx.x;
    const int CH = (N_NODES + 1023) / 1024;  // 49
    int start = t * CH, end = min(start + CH, N_NODES);
    int s = 0;
    for (int i = start; i < end; ++i) s += deg[i];
    ps[t] = s;
    __syncthreads();
    // Hillis-Steele inclusive scan over 1024 partials
    for (int off = 1; off < 1024; off <<= 1) {
        int v = (t >= off) ? ps[t - off] : 0;
        __syncthreads();
        ps[t] += v;
        __syncthreads();
    }
    int running = ps[t] - s;  // exclusive base for this chunk
    for (int i = start; i < end; ++i) {
        row_ptr[i] = running;
        cursor[i] = running;
        running += deg[i];
    }
    if (t == 1023) row_ptr[N_NODES] = ps[1023];
}

// ---- scatter edges into CSR slots ----
__global__ void build_csr_kernel(const int2* __restrict__ ei, const float* __restrict__ ew,
                                 int* __restrict__ cursor, int* __restrict__ csr_src,
                                 float* __restrict__ csr_w) {
    int e = blockIdx.x * blockDim.x + threadIdx.x;
    if (e >= N_EDGES) return;
    int2 sd = ei[e];
    int pos = atomicAdd(&cursor[sd.y], 1);
    csr_src[pos] = sd.x;
    csr_w[pos] = ew[e];
}

// ---- h = X @ W_in + b_in  (16 nodes per 256-thread block) ----
__global__ void gemm_in_kernel(const float* __restrict__ X, const float* __restrict__ W,
                               const float* __restrict__ b, float* __restrict__ h) {
    __shared__ float xs[16][IN_F];
    const int base = blockIdx.x * 16;
    const int t = threadIdx.x;
    // load 16x64 floats = 256 float4
    ((float4*)xs)[t] = ((const float4*)(X + (size_t)base * IN_F))[t];
    __syncthreads();
    const int f = t & (INT_F - 1);
    const int rg = t >> 7;  // 0..1, row group of 8
    float acc[8];
    const float bv = b[f];
#pragma unroll
    for (int j = 0; j < 8; ++j) acc[j] = bv;
    for (int k = 0; k < IN_F; ++k) {
        float w = W[k * INT_F + f];
#pragma unroll
        for (int j = 0; j < 8; ++j) acc[j] += xs[rg * 8 + j][k] * w;  // LDS broadcast per wave
    }
#pragma unroll
    for (int j = 0; j < 8; ++j) h[(size_t)(base + rg * 8 + j) * INT_F + f] = acc[j];
}

// ---- agg[n] = (1/deg) * sum_{e in CSR[n]} w_e * h[src_e]  (one wave per node, float2/lane) ----
__global__ void gather_kernel(const int* __restrict__ row_ptr, const int* __restrict__ csr_src,
                              const float* __restrict__ csr_w, const float2* __restrict__ h2,
                              float2* __restrict__ agg2) {
    int wid = (blockIdx.x * blockDim.x + threadIdx.x) >> 6;  // node
    int lane = threadIdx.x & 63;
    if (wid >= N_NODES) return;
    int s = row_ptr[wid], e = row_ptr[wid + 1];
    float ax = 0.0f, ay = 0.0f;
    for (int i = s; i < e; ++i) {
        int src = csr_src[i];
        float w = csr_w[i];
        float2 hv = h2[src * 64 + lane];  // coalesced 512B per wave
        ax += w * hv.x;
        ay += w * hv.y;
    }
    float inv = 1.0f / fmaxf((float)(e - s), 1.0f);
    float2 r;
    r.x = ax * inv;
    r.y = ay * inv;
    agg2[wid * 64 + lane] = r;
}

// ---- z = agg @ W + b ; h += lrelu(z)  (16 nodes per 256-thread block) ----
__global__ void layer_gemm_kernel(const float* __restrict__ agg, const float* __restrict__ W,
                                  const float* __restrict__ b, float* __restrict__ h) {
    __shared__ float as[16][INT_F];
    const int base = blockIdx.x * 16;
    const int t = threadIdx.x;
    // load 16x128 floats = 512 float4, 2 per thread
    const float4* A4 = (const float4*)(agg + (size_t)base * INT_F);
    ((float4*)as)[t] = A4[t];
    ((float4*)as)[t + 256] = A4[t + 256];
    __syncthreads();
    const int f = t & (INT_F - 1);
    const int rg = t >> 7;
    float acc[8];
    const float bv = b[f];
#pragma unroll
    for (int j = 0; j < 8; ++j) acc[j] = bv;
    for (int k = 0; k < INT_F; ++k) {
        float w = W[k * INT_F + f];
#pragma unroll
        for (int j = 0; j < 8; ++j) acc[j] += as[rg * 8 + j][k] * w;  // LDS broadcast per wave
    }
#pragma unroll
    for (int j = 0; j < 8; ++j) {
        size_t idx = (size_t)(base + rg * 8 + j) * INT_F + f;
        float z = acc[j];
        h[idx] += (z >= 0.0f) ? z : NEG_SLOPE * z;
    }
}

// ---- out = h @ W_out + b_out  (8 nodes per 256-thread block) ----
__global__ void gemm_out_kernel(const float* __restrict__ h, const float* __restrict__ W,
                                const float* __restrict__ b, float* __restrict__ out) {
    __shared__ float hr[8][INT_F];
    int base = blockIdx.x * 8;
    for (int t = threadIdx.x; t < 8 * INT_F; t += 256) {
        int n = t / INT_F, k = t % INT_F;
        int gn = base + n;
        hr[n][k] = (gn < N_NODES) ? h[(size_t)gn * INT_F + k] : 0.0f;
    }
    __syncthreads();
    int nl = threadIdx.x / OUT_F;  // 0..7
    int f = threadIdx.x % OUT_F;
    int node = base + nl;
    if (node >= N_NODES) return;
    float acc = b[f];
#pragma unroll 8
    for (int k = 0; k < INT_F; ++k) acc += hr[nl][k] * W[k * OUT_F + f];
    out[(size_t)node * OUT_F + f] = acc;
}

extern "C" void kernel_launch(void* const* d_in, const int* in_sizes, int n_in,
                              void* d_out, int out_size, void* d_ws, size_t ws_size,
                              hipStream_t stream) {
    const float* X        = (const float*)d_in[0];
    const int2*  ei       = (const int2*)d_in[1];
    const float* ew       = (const float*)d_in[2];
    const float* W_in     = (const float*)d_in[3];
    const float* b_in     = (const float*)d_in[4];
    const float* W_layers = (const float*)d_in[5];
    const float* b_layers = (const float*)d_in[6];
    const float* W_out    = (const float*)d_in[7];
    const float* b_out    = (const float*)d_in[8];

    float* out1 = (float*)d_out;                   // (N_NODES, OUT_F)
    float* h    = out1 + (size_t)N_NODES * OUT_F;  // (N_NODES, INT_F) -- second output doubles as h

    // workspace layout
    char* ws = (char*)d_ws;
    float* agg     = (float*)ws;                               ws += (size_t)N_NODES * INT_F * 4;  // 25.6 MB
    float* csr_w   = (float*)ws;                               ws += (size_t)N_EDGES * 4;          // 2.5 MB
    int*   csr_src = (int*)ws;                                 ws += (size_t)N_EDGES * 4;          // 2.5 MB
    int*   row_ptr = (int*)ws;                                 ws += (size_t)(N_NODES + 1) * 4;
    int*   cursor  = (int*)ws;                                 ws += (size_t)N_NODES * 4;
    int*   deg     = (int*)ws;                                 ws += (size_t)N_NODES * 4;

    // ---- build CSR (once per call) ----
    hipMemsetAsync(deg, 0, (size_t)N_NODES * 4, stream);
    deg_kernel<<<(N_EDGES + 255) / 256, 256, 0, stream>>>(ei, deg);
    scan_kernel<<<1, 1024, 0, stream>>>(deg, row_ptr, cursor);
    build_csr_kernel<<<(N_EDGES + 255) / 256, 256, 0, stream>>>(ei, ew, cursor, csr_src, csr_w);

    // ---- input projection ----
    gemm_in_kernel<<<N_NODES / 16, 256, 0, stream>>>(X, W_in, b_in, h);

    // ---- layers ----
    for (int i = 0; i < DEPTH; ++i) {
        gather_kernel<<<(N_NODES * 64 + 255) / 256, 256, 0, stream>>>(
            row_ptr, csr_src, csr_w, (const float2*)h, (float2*)agg);
        layer_gemm_kernel<<<N_NODES / 16, 256, 0, stream>>>(
            agg, W_layers + (size_t)i * INT_F * INT_F, b_layers + (size_t)i * INT_F, h);
    }

    // ---- output projection ----
    gemm_out_kernel<<<(N_NODES + 7) / 8, 256, 0, stream>>>(h, W_out, b_out, out1);
}

// Round 3
// 491.273 us; speedup vs baseline: 3.2995x; 1.3653x over previous
//
#include <hip/hip_runtime.h>

// Simple GNN: h = X@W_in+b; 4x { agg = segmean(w*h[src], dst); h += lrelu(agg@W_l+b_l) }
// out = (h@W_out+b_out, h)
// Round 3: hierarchical scan (kill 110us single-block scan), half-wave float4 gather,
//          32-node-batched layer GEMM.

#define N_NODES 50000
#define N_EDGES 625000
#define IN_F 64
#define INT_F 128
#define OUT_F 32
#define DEPTH 4
#define NEG_SLOPE 0.01f

#define SCAN_BLOCKS 196  // 196*256 = 50176 >= N_NODES

// ---- in-degree (int) ----
__global__ void deg_kernel(const int2* __restrict__ ei, int* __restrict__ deg) {
    int i = blockIdx.x * blockDim.x + threadIdx.x;
    if (i < N_EDGES) atomicAdd(&deg[ei[i].y], 1);
}

// ---- scan stage 1: per-block sum of 256 degrees ----
__global__ void scan1_kernel(const int* __restrict__ deg, int* __restrict__ partial) {
    int node = blockIdx.x * 256 + threadIdx.x;
    int v = (node < N_NODES) ? deg[node] : 0;
    __shared__ int sd[256];
    sd[threadIdx.x] = v;
    __syncthreads();
    for (int off = 128; off > 0; off >>= 1) {
        if (threadIdx.x < off) sd[threadIdx.x] += sd[threadIdx.x + off];
        __syncthreads();
    }
    if (threadIdx.x == 0) partial[blockIdx.x] = sd[0];
}

// ---- scan stage 2: single block scans the 196 partials -> exclusive block bases ----
__global__ void scan2_kernel(const int* __restrict__ partial, int* __restrict__ base,
                             int* __restrict__ row_ptr) {
    __shared__ int ps[256];
    int t = threadIdx.x;
    int v = (t < SCAN_BLOCKS) ? partial[t] : 0;
    ps[t] = v;
    __syncthreads();
    for (int off = 1; off < 256; off <<= 1) {
        int add = (t >= off) ? ps[t - off] : 0;
        __syncthreads();
        ps[t] += add;
        __syncthreads();
    }
    if (t < SCAN_BLOCKS) base[t] = ps[t] - v;  // exclusive
    if (t == SCAN_BLOCKS - 1) row_ptr[N_NODES] = ps[t];  // total = N_EDGES
}

// ---- scan stage 3: local inclusive scan + base -> row_ptr, cursor ----
__global__ void scan3_kernel(const int* __restrict__ deg, const int* __restrict__ base,
                             int* __restrict__ row_ptr, int* __restrict__ cursor) {
    int node = blockIdx.x * 256 + threadIdx.x;
    int t = threadIdx.x;
    int d = (node < N_NODES) ? deg[node] : 0;
    __shared__ int ps[256];
    ps[t] = d;
    __syncthreads();
    for (int off = 1; off < 256; off <<= 1) {
        int add = (t >= off) ? ps[t - off] : 0;
        __syncthreads();
        ps[t] += add;
        __syncthreads();
    }
    if (node < N_NODES) {
        int excl = base[blockIdx.x] + ps[t] - d;
        row_ptr[node] = excl;
        cursor[node] = excl;
    }
}

// ---- scatter edges into CSR slots ----
__global__ void build_csr_kernel(const int2* __restrict__ ei, const float* __restrict__ ew,
                                 int* __restrict__ cursor, int* __restrict__ csr_src,
                                 float* __restrict__ csr_w) {
    int e = blockIdx.x * blockDim.x + threadIdx.x;
    if (e >= N_EDGES) return;
    int2 sd = ei[e];
    int pos = atomicAdd(&cursor[sd.y], 1);
    csr_src[pos] = sd.x;
    csr_w[pos] = ew[e];
}

// ---- h = X @ W_in + b_in  (16 nodes per 256-thread block) ----
__global__ void gemm_in_kernel(const float* __restrict__ X, const float* __restrict__ W,
                               const float* __restrict__ b, float* __restrict__ h) {
    __shared__ float xs[16][IN_F];
    const int base = blockIdx.x * 16;
    const int t = threadIdx.x;
    ((float4*)xs)[t] = ((const float4*)(X + (size_t)base * IN_F))[t];
    __syncthreads();
    const int f = t & (INT_F - 1);
    const int rg = t >> 7;  // 0..1 -> rows rg*8..rg*8+7
    float acc[8];
    const float bv = b[f];
#pragma unroll
    for (int j = 0; j < 8; ++j) acc[j] = bv;
    for (int k = 0; k < IN_F; ++k) {
        float w = W[k * INT_F + f];
#pragma unroll
        for (int j = 0; j < 8; ++j) acc[j] += xs[rg * 8 + j][k] * w;
    }
#pragma unroll
    for (int j = 0; j < 8; ++j) h[(size_t)(base + rg * 8 + j) * INT_F + f] = acc[j];
}

// ---- agg[n] = (1/deg) * sum w_e * h[src_e]  (half-wave per node, float4/lane) ----
__global__ void gather_kernel(const int* __restrict__ row_ptr, const int* __restrict__ csr_src,
                              const float* __restrict__ csr_w, const float4* __restrict__ h4,
                              float4* __restrict__ agg4) {
    int gid = blockIdx.x * blockDim.x + threadIdx.x;
    int node = gid >> 5;  // half-wave per node
    int l = threadIdx.x & 31;
    if (node >= N_NODES) return;
    int s = row_ptr[node], e = row_ptr[node + 1];
    float4 acc = {0.f, 0.f, 0.f, 0.f};
    int i = s;
    for (; i + 1 < e; i += 2) {
        int src0 = csr_src[i], src1 = csr_src[i + 1];
        float w0 = csr_w[i], w1 = csr_w[i + 1];
        float4 a = h4[(size_t)src0 * 32 + l];
        float4 c = h4[(size_t)src1 * 32 + l];
        acc.x += w0 * a.x + w1 * c.x;
        acc.y += w0 * a.y + w1 * c.y;
        acc.z += w0 * a.z + w1 * c.z;
        acc.w += w0 * a.w + w1 * c.w;
    }
    if (i < e) {
        int src = csr_src[i];
        float w = csr_w[i];
        float4 a = h4[(size_t)src * 32 + l];
        acc.x += w * a.x; acc.y += w * a.y; acc.z += w * a.z; acc.w += w * a.w;
    }
    float inv = 1.0f / fmaxf((float)(e - s), 1.0f);
    acc.x *= inv; acc.y *= inv; acc.z *= inv; acc.w *= inv;
    agg4[(size_t)node * 32 + l] = acc;
}

// ---- z = agg @ W + b ; h += lrelu(z)  (32 nodes per 256-thread block) ----
__global__ void layer_gemm_kernel(const float* __restrict__ agg, const float* __restrict__ W,
                                  const float* __restrict__ b, float* __restrict__ h) {
    __shared__ float as[32][INT_F];
    const int base = blockIdx.x * 32;
    const int t = threadIdx.x;
    const float4* A4 = (const float4*)(agg + (size_t)base * INT_F);
#pragma unroll
    for (int j = 0; j < 4; ++j) ((float4*)as)[t + j * 256] = A4[t + j * 256];
    __syncthreads();
    const int f = t & (INT_F - 1);
    const int rg = t >> 7;  // 0..1 -> rows rg*16..rg*16+15
    float acc[16];
    const float bv = b[f];
#pragma unroll
    for (int j = 0; j < 16; ++j) acc[j] = bv;
    for (int k = 0; k < INT_F; ++k) {
        float w = W[k * INT_F + f];
#pragma unroll
        for (int j = 0; j < 16; ++j) acc[j] += as[rg * 16 + j][k] * w;  // LDS broadcast
    }
#pragma unroll
    for (int j = 0; j < 16; ++j) {
        size_t idx = (size_t)(base + rg * 16 + j) * INT_F + f;
        float z = acc[j];
        h[idx] += (z >= 0.0f) ? z : NEG_SLOPE * z;
    }
}

// ---- out = h @ W_out + b_out  (8 nodes per 256-thread block) ----
__global__ void gemm_out_kernel(const float* __restrict__ h, const float* __restrict__ W,
                                const float* __restrict__ b, float* __restrict__ out) {
    __shared__ float hr[8][INT_F];
    int base = blockIdx.x * 8;
    for (int t = threadIdx.x; t < 8 * INT_F; t += 256) {
        int n = t / INT_F, k = t % INT_F;
        int gn = base + n;
        hr[n][k] = (gn < N_NODES) ? h[(size_t)gn * INT_F + k] : 0.0f;
    }
    __syncthreads();
    int nl = threadIdx.x / OUT_F;
    int f = threadIdx.x % OUT_F;
    int node = base + nl;
    if (node >= N_NODES) return;
    float acc = b[f];
#pragma unroll 8
    for (int k = 0; k < INT_F; ++k) acc += hr[nl][k] * W[k * OUT_F + f];
    out[(size_t)node * OUT_F + f] = acc;
}

extern "C" void kernel_launch(void* const* d_in, const int* in_sizes, int n_in,
                              void* d_out, int out_size, void* d_ws, size_t ws_size,
                              hipStream_t stream) {
    const float* X        = (const float*)d_in[0];
    const int2*  ei       = (const int2*)d_in[1];
    const float* ew       = (const float*)d_in[2];
    const float* W_in     = (const float*)d_in[3];
    const float* b_in     = (const float*)d_in[4];
    const float* W_layers = (const float*)d_in[5];
    const float* b_layers = (const float*)d_in[6];
    const float* W_out    = (const float*)d_in[7];
    const float* b_out    = (const float*)d_in[8];

    float* out1 = (float*)d_out;                   // (N_NODES, OUT_F)
    float* h    = out1 + (size_t)N_NODES * OUT_F;  // (N_NODES, INT_F) -- second output doubles as h

    // workspace layout
    char* ws = (char*)d_ws;
    float* agg     = (float*)ws;  ws += (size_t)N_NODES * INT_F * 4;  // 25.6 MB
    float* csr_w   = (float*)ws;  ws += (size_t)N_EDGES * 4;          // 2.5 MB
    int*   csr_src = (int*)ws;    ws += (size_t)N_EDGES * 4;          // 2.5 MB
    int*   row_ptr = (int*)ws;    ws += (size_t)(N_NODES + 1) * 4;
    int*   cursor  = (int*)ws;    ws += (size_t)N_NODES * 4;
    int*   deg     = (int*)ws;    ws += (size_t)N_NODES * 4;
    int*   partial = (int*)ws;    ws += (size_t)SCAN_BLOCKS * 4;
    int*   bbase   = (int*)ws;    ws += (size_t)SCAN_BLOCKS * 4;

    // ---- build CSR (once per call) ----
    hipMemsetAsync(deg, 0, (size_t)N_NODES * 4, stream);
    deg_kernel<<<(N_EDGES + 255) / 256, 256, 0, stream>>>(ei, deg);
    scan1_kernel<<<SCAN_BLOCKS, 256, 0, stream>>>(deg, partial);
    scan2_kernel<<<1, 256, 0, stream>>>(partial, bbase, row_ptr);
    scan3_kernel<<<SCAN_BLOCKS, 256, 0, stream>>>(deg, bbase, row_ptr, cursor);
    build_csr_kernel<<<(N_EDGES + 255) / 256, 256, 0, stream>>>(ei, ew, cursor, csr_src, csr_w);

    // ---- input projection ----
    gemm_in_kernel<<<N_NODES / 16, 256, 0, stream>>>(X, W_in, b_in, h);

    // ---- layers ----
    for (int i = 0; i < DEPTH; ++i) {
        gather_kernel<<<(N_NODES * 32 + 255) / 256, 256, 0, stream>>>(
            row_ptr, csr_src, csr_w, (const float4*)h, (float4*)agg);
        layer_gemm_kernel<<<(N_NODES + 31) / 32, 256, 0, stream>>>(
            agg, W_layers + (size_t)i * INT_F * INT_F, b_layers + (size_t)i * INT_F, h);
    }

    // ---- output projection ----
    gemm_out_kernel<<<(N_NODES + 7) / 8, 256, 0, stream>>>(h, W_out, b_out, out1);
}